// Round 9
// baseline (153.448 us; speedup 1.0000x reference)
//
#include <hip/hip_runtime.h>
#include <hip/hip_bf16.h>
#include <stdint.h>

#define DI __device__ __forceinline__

typedef __attribute__((ext_vector_type(8))) short short8;
typedef __attribute__((ext_vector_type(4))) short short4v;
typedef __attribute__((ext_vector_type(4))) float f32x4;
typedef __attribute__((ext_vector_type(16))) float f32x16;
typedef __attribute__((ext_vector_type(4))) unsigned uint4v;

static constexpr int TT = 4096;   // seq len
static constexpr int CC = 1024;   // n_embed
static constexpr int HH = 64;     // head size

DI short f2b(float x) {
  __hip_bfloat16 h = __float2bfloat16(x);
  return __builtin_bit_cast(short, h);
}
DI unsigned packbf(float lo, float hi) {
  return (unsigned)(unsigned short)f2b(lo) |
         ((unsigned)(unsigned short)f2b(hi) << 16);
}

DI f32x4 MFMA(short8 a, short8 b, f32x4 c) {
  return __builtin_amdgcn_mfma_f32_16x16x32_bf16(a, b, c, 0, 0, 0);
}
DI f32x16 MFMA32(short8 a, short8 b, f32x16 c) {
  return __builtin_amdgcn_mfma_f32_32x32x16_bf16(a, b, c, 0, 0, 0);
}

DI void gload_lds16(const void* g, void* l) {
  __builtin_amdgcn_global_load_lds(
      (__attribute__((address_space(1))) void*)(void*)(uintptr_t)g,
      (__attribute__((address_space(3))) void*)(void*)(uintptr_t)l, 16, 0, 0);
}

// ---------------------------------------------------------------------------
// Kernel 0: transpose weights W[k][n] f32 -> Wt[mat][n][k] bf16  (3*64*1024)
// ---------------------------------------------------------------------------
__global__ __launch_bounds__(256) void prep_wt(const float* __restrict__ Wq,
                                               const float* __restrict__ Wk,
                                               const float* __restrict__ Wv,
                                               short* __restrict__ Wt) {
  int o = blockIdx.x * 256 + threadIdx.x;       // < 196608
  int mat = o >> 16;
  int rem = o & 65535;
  int n = rem >> 10;
  int k = rem & 1023;
  const float* W = (mat == 0) ? Wq : ((mat == 1) ? Wk : Wv);
  Wt[o] = f2b(W[k * HH + n]);
}

// ---------------------------------------------------------------------------
// Kernel 1: fused QKV projection — 2-phase double-buffered LDS GEMM
// (validated R8; frozen this round).
// ---------------------------------------------------------------------------
__global__ __launch_bounds__(512, 2) void qkv_gemm(const float* __restrict__ x,
                                                   const short* __restrict__ Wt,
                                                   const float* __restrict__ bq,
                                                   const float* __restrict__ bk,
                                                   const float* __restrict__ bv,
                                                   short* __restrict__ qbuf,
                                                   short* __restrict__ kbuf,
                                                   short* __restrict__ vT) {
  __shared__ short lds_a[2 * 64 * 64];     // [buf][row][k] 128B rows, swizzled
  __shared__ short lds_b[2 * 192 * 64];    // [buf][n][k] 128B rows, swizzled

  const int tid = threadIdx.x;
  const int w = tid >> 6, lane = tid & 63;
  const int wr = w >> 2, wc = w & 3;
  const int c = lane & 15, g = lane >> 4;
  const int m0 = blockIdx.x * 64;
  const int ar = tid >> 3, as = tid & 7;   // A-stage: row, k-segment
  const int sw = (c & 7) << 4;

  f32x4 acc[2][3] = {};   // [mf][nf]

  // ---- prologue: stage K-step 0 into buffer 0
  {
    const float* ap = x + (size_t)(m0 + ar) * CC + 8 * as;
    float4 a0 = ((const float4*)ap)[0];
    float4 a1 = ((const float4*)ap)[1];
    uint2 d0, d1;
    d0.x = packbf(a0.x, a0.y); d0.y = packbf(a0.z, a0.w);
    d1.x = packbf(a1.x, a1.y); d1.y = packbf(a1.z, a1.w);
    uint4 pk = {d0.x, d0.y, d1.x, d1.y};
    *(uint4*)((char*)lds_a + ar * 128 + ((16 * as) ^ ((ar & 7) << 4))) = pk;
#pragma unroll
    for (int ch = 0; ch < 3; ++ch) {
      int n = ch * 64 + w * 8 + (lane >> 3);
      int q = lane & 7;
      gload_lds16(Wt + n * CC + 8 * (q ^ (n & 7)),
                  lds_b + (ch * 512 + w * 64) * 8);
    }
  }
  __syncthreads();

  for (int t = 0; t < 16; ++t) {
    const int cur = t & 1, nxt = cur ^ 1;
    const short* Ab = lds_a + cur * 4096;
    const short* Bb = lds_b + cur * 12288;

    // ---- (1) issue next A-tile global loads (consumed after compute, T14)
    float4 xa0, xa1;
    if (t + 1 < 16) {
      const float* ap = x + (size_t)(m0 + ar) * CC + (t + 1) * 64 + 8 * as;
      xa0 = ((const float4*)ap)[0];
      xa1 = ((const float4*)ap)[1];
      // ---- (2) issue next B-tile global_load_lds (drained by the barrier)
#pragma unroll
      for (int ch = 0; ch < 3; ++ch) {
        int n = ch * 64 + w * 8 + (lane >> 3);
        int q = lane & 7;
        gload_lds16(Wt + n * CC + (t + 1) * 64 + 8 * (q ^ (n & 7)),
                    lds_b + nxt * 12288 + (ch * 512 + w * 64) * 8);
      }
    }

    // ---- (3) fragments from LDS + MFMA
    short8 afr[2][2], bfr[3][2];
#pragma unroll
    for (int mf = 0; mf < 2; ++mf)
#pragma unroll
      for (int ks = 0; ks < 2; ++ks) {
        int row = 32 * wr + 16 * mf + c;
        afr[mf][ks] = *(const short8*)((const char*)Ab + row * 128 +
                                       ((ks * 64 + g * 16) ^ sw));
      }
#pragma unroll
    for (int nf = 0; nf < 3; ++nf)
#pragma unroll
      for (int ks = 0; ks < 2; ++ks) {
        int n = 48 * wc + 16 * nf + c;
        bfr[nf][ks] = *(const short8*)((const char*)Bb + n * 128 +
                                       ((ks * 64 + g * 16) ^ sw));
      }
#pragma unroll
    for (int ks = 0; ks < 2; ++ks)
#pragma unroll
      for (int mf = 0; mf < 2; ++mf)
#pragma unroll
        for (int nf = 0; nf < 3; ++nf)
          acc[mf][nf] = MFMA(afr[mf][ks], bfr[nf][ks], acc[mf][nf]);

    // ---- (4) convert + write next A-tile to LDS (loads landed under compute)
    if (t + 1 < 16) {
      uint2 d0, d1;
      d0.x = packbf(xa0.x, xa0.y); d0.y = packbf(xa0.z, xa0.w);
      d1.x = packbf(xa1.x, xa1.y); d1.y = packbf(xa1.z, xa1.w);
      uint4 pk = {d0.x, d0.y, d1.x, d1.y};
      *(uint4*)((char*)lds_a + nxt * 8192 + ar * 128 +
                ((16 * as) ^ ((ar & 7) << 4))) = pk;
    }
    // ---- (5) barrier (drains gload_lds + ds_writes)
    __syncthreads();
  }

  // ---- epilogue: +bias, scale (q), bf16 stores; V written transposed
  const float QSCALE = 0.125f * 1.44269504088896340736f;  // 1/sqrt(64)*log2(e)
  const int bb = m0 >> 12;
  const int t0 = m0 & 4095;
#pragma unroll
  for (int nf = 0; nf < 3; ++nf) {
    const int col0 = 48 * wc + 16 * nf;
    const int mat = col0 >> 6;
    const int n = (col0 & 63) + c;
    const float* bp = (mat == 0) ? bq : ((mat == 1) ? bk : bv);
    const float bias = bp[n];
    if (mat < 2) {
      short* op = (mat == 0) ? qbuf : kbuf;
      const float scale = (mat == 0) ? QSCALE : 1.0f;
#pragma unroll
      for (int mf = 0; mf < 2; ++mf)
#pragma unroll
        for (int r = 0; r < 4; ++r) {
          int mrow = m0 + 32 * wr + 16 * mf + 4 * g + r;
          op[(size_t)mrow * HH + n] = f2b((acc[mf][nf][r] + bias) * scale);
        }
    } else {
#pragma unroll
      for (int mf = 0; mf < 2; ++mf) {
        short4v pv;
#pragma unroll
        for (int r = 0; r < 4; ++r) pv[r] = f2b(acc[mf][nf][r] + bias);
        *(short4v*)(vT + (size_t)(bb * HH + n) * TT + t0 + 32 * wr + 16 * mf +
                    4 * g) = pv;
      }
    }
  }
}

// ---------------------------------------------------------------------------
// Kernel 2: causal flash attention, swapped-operand 32x32 MFMA core.
// R7 structure with the P^T LDS roundtrip replaced by in-register
// cvt_pk + permlane32_swap exchange (T12). All swap operands are DISTINCT
// values (no register-coalescing hazard — the R4 NaN mechanism).
// Softmax max/sum still via __shfl_xor(.,32) (R7-verified).
// ---------------------------------------------------------------------------
__global__ __launch_bounds__(256) void attn(const short* __restrict__ qbuf,
                                            const short* __restrict__ kbuf,
                                            const short* __restrict__ vT,
                                            float* __restrict__ out) {
  __shared__ float4 lds_od[3 * 8 * 64];     // merge O^T from waves 1..3
  __shared__ float lds_ml[3 * 128];         // merge m,l

  const int id = blockIdx.x;                 // 0..511
  const int xcd = id & 7, slot = id >> 3;    // CU c hosts slots c and c+32
  const int rix = (slot < 32) ? slot : (95 - slot);  // pair {s, 63-s}
  const int rank = rix * 8 + xcd;            // desc-sorted work rank
  const int jj = 127 - (rank >> 2);          // q-tile (32 rows)
  const int bb = rank & 3;                   // batch

  const int tid = threadIdx.x;
  const int w = tid >> 6, lane = tid & 63;
  const int ql = lane & 31;
  const int hi = lane >> 5;
  const int q0 = jj * 32;
  const int nT = jj + 1;                     // causal 32-kt tiles
  const int tlo = (w * nT) >> 2, thi = ((w + 1) * nT) >> 2;

  // Q fragments (B-operand): B[h = 16*kk + 8*hi + j][col = ql]
  const short* qr = qbuf + (size_t)(bb * TT + q0 + ql) * HH + 8 * hi;
  const short8 qf0 = *(const short8*)(qr);
  const short8 qf1 = *(const short8*)(qr + 16);
  const short8 qf2 = *(const short8*)(qr + 32);
  const short8 qf3 = *(const short8*)(qr + 48);

  const short* kB = kbuf + (size_t)bb * TT * HH;
  const short* vB = vT + (size_t)bb * HH * TT;

  f32x16 accO0 = {0,0,0,0,0,0,0,0,0,0,0,0,0,0,0,0};
  f32x16 accO1 = {0,0,0,0,0,0,0,0,0,0,0,0,0,0,0,0};
  float m = -INFINITY, l = 0.f;

  for (int t = tlo; t < thi; ++t) {
    const int kv0 = t * 32;
    // ---- K fragments (A-operand): A[row = kt_local = ql][k = h = 8*hi + j]
    const short* krow = kB + (size_t)(kv0 + ql) * HH + 8 * hi;
    short8 kf0 = *(const short8*)(krow);
    short8 kf1 = *(const short8*)(krow + 16);
    short8 kf2 = *(const short8*)(krow + 32);
    short8 kf3 = *(const short8*)(krow + 48);
    // ---- V fragments (A-operand): A[row = h' = ql][k = kt = 16*kk + 8*hi + j]
    const short* vrow = vB + (size_t)ql * TT + kv0 + 8 * hi;
    short8 vf00 = *(const short8*)(vrow);            // h'=ql      kk=0
    short8 vf01 = *(const short8*)(vrow + 16);       // h'=ql      kk=1
    short8 vf10 = *(const short8*)(vrow + 32 * TT);  // h'=32+ql   kk=0
    short8 vf11 = *(const short8*)(vrow + 32 * TT + 16);

    // ---- S^T[kt][q] (exp2 domain; scale folded into q)
    f32x16 sc = {0,0,0,0,0,0,0,0,0,0,0,0,0,0,0,0};
    sc = MFMA32(kf0, qf0, sc);
    sc = MFMA32(kf1, qf1, sc);
    sc = MFMA32(kf2, qf2, sc);
    sc = MFMA32(kf3, qf3, sc);

    // ---- causal mask (diagonal tile): kt = kv0 + (r&3) + 8*(r>>2) + 4*hi
    if (t == nT - 1) {
#pragma unroll
      for (int r = 0; r < 16; ++r) {
        int kt = kv0 + (r & 3) + 8 * (r >> 2) + 4 * hi;
        if (kt > q0 + ql) sc[r] = -INFINITY;
      }
    }

    // ---- online softmax: lane owns one q-row; cross-half via shfl_xor(32)
    float tm = fmaxf(fmaxf(fmaxf(sc[0], sc[1]), fmaxf(sc[2], sc[3])),
                     fmaxf(fmaxf(sc[4], sc[5]), fmaxf(sc[6], sc[7])));
    float tm2 = fmaxf(fmaxf(fmaxf(sc[8], sc[9]), fmaxf(sc[10], sc[11])),
                      fmaxf(fmaxf(sc[12], sc[13]), fmaxf(sc[14], sc[15])));
    tm = fmaxf(tm, tm2);
    tm = fmaxf(tm, __shfl_xor(tm, 32));      // full 32-row max, both halves
    if (__any(tm > m + 8.0f)) {              // defer-max (THR=8, exp2 domain)
      float mn = fmaxf(m, tm);
      float al = exp2f(m - mn);
      l *= al;
#pragma unroll
      for (int r = 0; r < 16; ++r) { accO0[r] *= al; accO1[r] *= al; }
      m = mn;
    }
    float p[16];
    float rs = 0.f;
#pragma unroll
    for (int r = 0; r < 16; ++r) {
      p[r] = exp2f(sc[r] - m);
      rs += p[r];
    }
    l += rs + __shfl_xor(rs, 32);

    // ---- P -> bf16 B-operand via cvt_pk + permlane32_swap (T12).
    // After swap(a,b): lane<32: a=own, b=partner-lo-image; lane>=32:
    // a=partner-hi-image, b=own — exactly pf layout B[k=8*hi+j][col=ql].
    unsigned a0 = packbf(p[0], p[1]),   b0 = packbf(p[4], p[5]);
    unsigned a1 = packbf(p[2], p[3]),   b1 = packbf(p[6], p[7]);
    unsigned a2 = packbf(p[8], p[9]),   b2 = packbf(p[12], p[13]);
    unsigned a3 = packbf(p[10], p[11]), b3 = packbf(p[14], p[15]);
    asm("v_permlane32_swap_b32 %0, %1" : "+v"(a0), "+v"(b0));
    asm("v_permlane32_swap_b32 %0, %1" : "+v"(a1), "+v"(b1));
    asm("v_permlane32_swap_b32 %0, %1" : "+v"(a2), "+v"(b2));
    asm("v_permlane32_swap_b32 %0, %1" : "+v"(a3), "+v"(b3));
    uint4v u0; u0[0] = a0; u0[1] = a1; u0[2] = b0; u0[3] = b1;
    uint4v u1; u1[0] = a2; u1[1] = a3; u1[2] = b2; u1[3] = b3;
    short8 pf0 = __builtin_bit_cast(short8, u0);   // kt chunk [kv0, kv0+16)
    short8 pf1 = __builtin_bit_cast(short8, u1);   // kt chunk [kv0+16, kv0+32)

    // ---- O^T += V^T P
    accO0 = MFMA32(vf00, pf0, accO0);
    accO0 = MFMA32(vf01, pf1, accO0);
    accO1 = MFMA32(vf10, pf0, accO1);
    accO1 = MFMA32(vf11, pf1, accO1);
  }

  // ---- 4-way merge: waves 1..3 dump (O^T, m, l); wave 0 combines + stores
  __syncthreads();
  if (w > 0) {
#pragma unroll
    for (int rq = 0; rq < 4; ++rq) {
      float4 t0, t1;
      t0.x = accO0[4 * rq]; t0.y = accO0[4 * rq + 1];
      t0.z = accO0[4 * rq + 2]; t0.w = accO0[4 * rq + 3];
      t1.x = accO1[4 * rq]; t1.y = accO1[4 * rq + 1];
      t1.z = accO1[4 * rq + 2]; t1.w = accO1[4 * rq + 3];
      lds_od[((w - 1) * 8 + rq) * 64 + lane] = t0;
      lds_od[((w - 1) * 8 + 4 + rq) * 64 + lane] = t1;
    }
    lds_ml[(w - 1) * 128 + lane] = m;
    lds_ml[(w - 1) * 128 + 64 + lane] = l;
  }
  __syncthreads();
  if (w == 0) {
    float m1 = lds_ml[lane],       l1 = lds_ml[64 + lane];
    float m2 = lds_ml[128 + lane], l2 = lds_ml[192 + lane];
    float m3 = lds_ml[256 + lane], l3 = lds_ml[320 + lane];
    float ms = fmaxf(fmaxf(m, m1), fmaxf(m2, m3));
    float c0 = exp2f(m - ms), c1 = exp2f(m1 - ms);
    float c2 = exp2f(m2 - ms), c3 = exp2f(m3 - ms);
    float inv = 1.0f / (c0 * l + c1 * l1 + c2 * l2 + c3 * l3);
    float* orow = out + (size_t)(bb * TT + q0 + ql) * HH;
#pragma unroll
    for (int rq = 0; rq < 8; ++rq) {
      float4 v1 = lds_od[(0 * 8 + rq) * 64 + lane];
      float4 v2 = lds_od[(1 * 8 + rq) * 64 + lane];
      float4 v3 = lds_od[(2 * 8 + rq) * 64 + lane];
      float o0, o1, o2, o3;
      if (rq < 4) {
        o0 = accO0[4 * (rq & 3)];     o1 = accO0[4 * (rq & 3) + 1];
        o2 = accO0[4 * (rq & 3) + 2]; o3 = accO0[4 * (rq & 3) + 3];
      } else {
        o0 = accO1[4 * (rq & 3)];     o1 = accO1[4 * (rq & 3) + 1];
        o2 = accO1[4 * (rq & 3) + 2]; o3 = accO1[4 * (rq & 3) + 3];
      }
      float4 res;
      res.x = (c0 * o0 + c1 * v1.x + c2 * v2.x + c3 * v3.x) * inv;
      res.y = (c0 * o1 + c1 * v1.y + c2 * v2.y + c3 * v3.y) * inv;
      res.z = (c0 * o2 + c1 * v1.z + c2 * v2.z + c3 * v3.z) * inv;
      res.w = (c0 * o3 + c1 * v1.w + c2 * v2.w + c3 * v3.w) * inv;
      const int ht = rq >> 2, r2 = rq & 3;
      *(float4*)(orow + 32 * ht + 8 * r2 + 4 * hi) = res;
    }
  }
}

// ---------------------------------------------------------------------------
extern "C" void kernel_launch(void* const* d_in, const int* in_sizes, int n_in,
                              void* d_out, int out_size, void* d_ws, size_t ws_size,
                              hipStream_t stream) {
  const float* x  = (const float*)d_in[0];
  const float* Wq = (const float*)d_in[1];
  const float* bq = (const float*)d_in[2];
  const float* Wk = (const float*)d_in[3];
  const float* bk = (const float*)d_in[4];
  const float* Wv = (const float*)d_in[5];
  const float* bv = (const float*)d_in[6];
  float* out = (float*)d_out;

  char* ws = (char*)d_ws;
  short* Wt = (short*)ws;                           // 3*64*1024 bf16 = 384 KB
  short* qb = (short*)(ws + 393216);                // 16384*64 bf16 = 2 MB
  short* kb = qb + 16384 * 64;
  short* vT = kb + 16384 * 64;                      // total ~6.7 MB

  prep_wt<<<dim3(768), dim3(256), 0, stream>>>(Wq, Wk, Wv, Wt);
  qkv_gemm<<<dim3(256), dim3(512), 0, stream>>>(x, Wt, bq, bk, bv, qb, kb, vT);
  attn<<<dim3(512), dim3(256), 0, stream>>>(qb, kb, vT, out);
}

// Round 10
// 152.782 us; speedup vs baseline: 1.0044x; 1.0044x over previous
//
#include <hip/hip_runtime.h>
#include <hip/hip_bf16.h>
#include <stdint.h>

#define DI __device__ __forceinline__

typedef __attribute__((ext_vector_type(8))) short short8;
typedef __attribute__((ext_vector_type(4))) short short4v;
typedef __attribute__((ext_vector_type(4))) float f32x4;
typedef __attribute__((ext_vector_type(16))) float f32x16;
typedef __attribute__((ext_vector_type(4))) unsigned uint4v;

static constexpr int TT = 4096;   // seq len
static constexpr int CC = 1024;   // n_embed
static constexpr int HH = 64;     // head size

DI short f2b(float x) {
  __hip_bfloat16 h = __float2bfloat16(x);
  return __builtin_bit_cast(short, h);
}
DI unsigned packbf(float lo, float hi) {
  return (unsigned)(unsigned short)f2b(lo) |
         ((unsigned)(unsigned short)f2b(hi) << 16);
}

DI f32x4 MFMA(short8 a, short8 b, f32x4 c) {
  return __builtin_amdgcn_mfma_f32_16x16x32_bf16(a, b, c, 0, 0, 0);
}
DI f32x16 MFMA32(short8 a, short8 b, f32x16 c) {
  return __builtin_amdgcn_mfma_f32_32x32x16_bf16(a, b, c, 0, 0, 0);
}

DI void gload_lds16(const void* g, void* l) {
  __builtin_amdgcn_global_load_lds(
      (__attribute__((address_space(1))) void*)(void*)(uintptr_t)g,
      (__attribute__((address_space(3))) void*)(void*)(uintptr_t)l, 16, 0, 0);
}

// ---------------------------------------------------------------------------
// Kernel 0: transpose weights W[k][n] f32 -> Wt[mat][n][k] bf16  (3*64*1024)
// ---------------------------------------------------------------------------
__global__ __launch_bounds__(256) void prep_wt(const float* __restrict__ Wq,
                                               const float* __restrict__ Wk,
                                               const float* __restrict__ Wv,
                                               short* __restrict__ Wt) {
  int o = blockIdx.x * 256 + threadIdx.x;       // < 196608
  int mat = o >> 16;
  int rem = o & 65535;
  int n = rem >> 10;
  int k = rem & 1023;
  const float* W = (mat == 0) ? Wq : ((mat == 1) ? Wk : Wv);
  Wt[o] = f2b(W[k * HH + n]);
}

// ---------------------------------------------------------------------------
// Kernel 1: fused QKV projection — 2-phase double-buffered LDS GEMM
// (validated R8; frozen).
// ---------------------------------------------------------------------------
__global__ __launch_bounds__(512, 2) void qkv_gemm(const float* __restrict__ x,
                                                   const short* __restrict__ Wt,
                                                   const float* __restrict__ bq,
                                                   const float* __restrict__ bk,
                                                   const float* __restrict__ bv,
                                                   short* __restrict__ qbuf,
                                                   short* __restrict__ kbuf,
                                                   short* __restrict__ vT) {
  __shared__ short lds_a[2 * 64 * 64];     // [buf][row][k] 128B rows, swizzled
  __shared__ short lds_b[2 * 192 * 64];    // [buf][n][k] 128B rows, swizzled

  const int tid = threadIdx.x;
  const int w = tid >> 6, lane = tid & 63;
  const int wr = w >> 2, wc = w & 3;
  const int c = lane & 15, g = lane >> 4;
  const int m0 = blockIdx.x * 64;
  const int ar = tid >> 3, as = tid & 7;   // A-stage: row, k-segment
  const int sw = (c & 7) << 4;

  f32x4 acc[2][3] = {};   // [mf][nf]

  // ---- prologue: stage K-step 0 into buffer 0
  {
    const float* ap = x + (size_t)(m0 + ar) * CC + 8 * as;
    float4 a0 = ((const float4*)ap)[0];
    float4 a1 = ((const float4*)ap)[1];
    uint2 d0, d1;
    d0.x = packbf(a0.x, a0.y); d0.y = packbf(a0.z, a0.w);
    d1.x = packbf(a1.x, a1.y); d1.y = packbf(a1.z, a1.w);
    uint4 pk = {d0.x, d0.y, d1.x, d1.y};
    *(uint4*)((char*)lds_a + ar * 128 + ((16 * as) ^ ((ar & 7) << 4))) = pk;
#pragma unroll
    for (int ch = 0; ch < 3; ++ch) {
      int n = ch * 64 + w * 8 + (lane >> 3);
      int q = lane & 7;
      gload_lds16(Wt + n * CC + 8 * (q ^ (n & 7)),
                  lds_b + (ch * 512 + w * 64) * 8);
    }
  }
  __syncthreads();

  for (int t = 0; t < 16; ++t) {
    const int cur = t & 1, nxt = cur ^ 1;
    const short* Ab = lds_a + cur * 4096;
    const short* Bb = lds_b + cur * 12288;

    // ---- (1) issue next A-tile global loads (consumed after compute, T14)
    float4 xa0, xa1;
    if (t + 1 < 16) {
      const float* ap = x + (size_t)(m0 + ar) * CC + (t + 1) * 64 + 8 * as;
      xa0 = ((const float4*)ap)[0];
      xa1 = ((const float4*)ap)[1];
      // ---- (2) issue next B-tile global_load_lds (drained by the barrier)
#pragma unroll
      for (int ch = 0; ch < 3; ++ch) {
        int n = ch * 64 + w * 8 + (lane >> 3);
        int q = lane & 7;
        gload_lds16(Wt + n * CC + (t + 1) * 64 + 8 * (q ^ (n & 7)),
                    lds_b + nxt * 12288 + (ch * 512 + w * 64) * 8);
      }
    }

    // ---- (3) fragments from LDS + MFMA
    short8 afr[2][2], bfr[3][2];
#pragma unroll
    for (int mf = 0; mf < 2; ++mf)
#pragma unroll
      for (int ks = 0; ks < 2; ++ks) {
        int row = 32 * wr + 16 * mf + c;
        afr[mf][ks] = *(const short8*)((const char*)Ab + row * 128 +
                                       ((ks * 64 + g * 16) ^ sw));
      }
#pragma unroll
    for (int nf = 0; nf < 3; ++nf)
#pragma unroll
      for (int ks = 0; ks < 2; ++ks) {
        int n = 48 * wc + 16 * nf + c;
        bfr[nf][ks] = *(const short8*)((const char*)Bb + n * 128 +
                                       ((ks * 64 + g * 16) ^ sw));
      }
#pragma unroll
    for (int ks = 0; ks < 2; ++ks)
#pragma unroll
      for (int mf = 0; mf < 2; ++mf)
#pragma unroll
        for (int nf = 0; nf < 3; ++nf)
          acc[mf][nf] = MFMA(afr[mf][ks], bfr[nf][ks], acc[mf][nf]);

    // ---- (4) convert + write next A-tile to LDS (loads landed under compute)
    if (t + 1 < 16) {
      uint2 d0, d1;
      d0.x = packbf(xa0.x, xa0.y); d0.y = packbf(xa0.z, xa0.w);
      d1.x = packbf(xa1.x, xa1.y); d1.y = packbf(xa1.z, xa1.w);
      uint4 pk = {d0.x, d0.y, d1.x, d1.y};
      *(uint4*)((char*)lds_a + nxt * 8192 + ar * 128 +
                ((16 * as) ^ ((ar & 7) << 4))) = pk;
    }
    // ---- (5) barrier (drains gload_lds + ds_writes)
    __syncthreads();
  }

  // ---- epilogue: +bias, scale (q), bf16 stores; V written transposed
  const float QSCALE = 0.125f * 1.44269504088896340736f;  // 1/sqrt(64)*log2(e)
  const int bb = m0 >> 12;
  const int t0 = m0 & 4095;
#pragma unroll
  for (int nf = 0; nf < 3; ++nf) {
    const int col0 = 48 * wc + 16 * nf;
    const int mat = col0 >> 6;
    const int n = (col0 & 63) + c;
    const float* bp = (mat == 0) ? bq : ((mat == 1) ? bk : bv);
    const float bias = bp[n];
    if (mat < 2) {
      short* op = (mat == 0) ? qbuf : kbuf;
      const float scale = (mat == 0) ? QSCALE : 1.0f;
#pragma unroll
      for (int mf = 0; mf < 2; ++mf)
#pragma unroll
        for (int r = 0; r < 4; ++r) {
          int mrow = m0 + 32 * wr + 16 * mf + 4 * g + r;
          op[(size_t)mrow * HH + n] = f2b((acc[mf][nf][r] + bias) * scale);
        }
    } else {
#pragma unroll
      for (int mf = 0; mf < 2; ++mf) {
        short4v pv;
#pragma unroll
        for (int r = 0; r < 4; ++r) pv[r] = f2b(acc[mf][nf][r] + bias);
        *(short4v*)(vT + (size_t)(bb * HH + n) * TT + t0 + 32 * wr + 16 * mf +
                    4 * g) = pv;
      }
    }
  }
}

// ---------------------------------------------------------------------------
// Kernel 2: causal flash attention, swapped-operand 32x32 MFMA core.
// NEW: 512-thread blocks, 8 waves = 8 KV-eighths of one 32-row q-job.
// 512 blocks -> 2 blocks/CU but 16 waves/CU (4/SIMD) for latency hiding.
// Per-tile math identical to R9 (verified): S^T = mfma32(K,Q), in-register
// softmax via shfl_xor(32), T12 cvt_pk+permlane32_swap P-exchange,
// O^T += mfma32(V^T,P). 8-way LDS merge at the end.
// ---------------------------------------------------------------------------
__global__ __launch_bounds__(512) void attn(const short* __restrict__ qbuf,
                                            const short* __restrict__ kbuf,
                                            const short* __restrict__ vT,
                                            float* __restrict__ out) {
  __shared__ float4 lds_od[7 * 8 * 64];     // merge O^T from waves 1..7
  __shared__ float lds_ml[7 * 128];         // merge m,l

  const int id = blockIdx.x;                 // 0..511
  const int xcd = id & 7, slot = id >> 3;    // CU c hosts slots c and c+32
  const int rix = (slot < 32) ? slot : (95 - slot);  // pair {s, 63-s}
  const int rank = rix * 8 + xcd;            // desc-sorted work rank
  const int jj = 127 - (rank >> 2);          // q-tile (32 rows)
  const int bb = rank & 3;                   // batch

  const int tid = threadIdx.x;
  const int w = tid >> 6, lane = tid & 63;   // w in 0..7
  const int ql = lane & 31;
  const int hi = lane >> 5;
  const int q0 = jj * 32;
  const int nT = jj + 1;                     // causal 32-kt tiles
  const int tlo = (w * nT) >> 3, thi = ((w + 1) * nT) >> 3;

  // Q fragments (B-operand): B[h = 16*kk + 8*hi + j][col = ql]
  const short* qr = qbuf + (size_t)(bb * TT + q0 + ql) * HH + 8 * hi;
  const short8 qf0 = *(const short8*)(qr);
  const short8 qf1 = *(const short8*)(qr + 16);
  const short8 qf2 = *(const short8*)(qr + 32);
  const short8 qf3 = *(const short8*)(qr + 48);

  const short* kB = kbuf + (size_t)bb * TT * HH;
  const short* vB = vT + (size_t)bb * HH * TT;

  f32x16 accO0 = {0,0,0,0,0,0,0,0,0,0,0,0,0,0,0,0};
  f32x16 accO1 = {0,0,0,0,0,0,0,0,0,0,0,0,0,0,0,0};
  float m = -INFINITY, l = 0.f;

  for (int t = tlo; t < thi; ++t) {
    const int kv0 = t * 32;
    // ---- K fragments (A-operand): A[row = kt_local = ql][k = h = 8*hi + j]
    const short* krow = kB + (size_t)(kv0 + ql) * HH + 8 * hi;
    short8 kf0 = *(const short8*)(krow);
    short8 kf1 = *(const short8*)(krow + 16);
    short8 kf2 = *(const short8*)(krow + 32);
    short8 kf3 = *(const short8*)(krow + 48);
    // ---- V fragments (A-operand): A[row = h' = ql][k = kt = 16*kk + 8*hi + j]
    const short* vrow = vB + (size_t)ql * TT + kv0 + 8 * hi;
    short8 vf00 = *(const short8*)(vrow);            // h'=ql      kk=0
    short8 vf01 = *(const short8*)(vrow + 16);       // h'=ql      kk=1
    short8 vf10 = *(const short8*)(vrow + 32 * TT);  // h'=32+ql   kk=0
    short8 vf11 = *(const short8*)(vrow + 32 * TT + 16);

    // ---- S^T[kt][q] (exp2 domain; scale folded into q)
    f32x16 sc = {0,0,0,0,0,0,0,0,0,0,0,0,0,0,0,0};
    sc = MFMA32(kf0, qf0, sc);
    sc = MFMA32(kf1, qf1, sc);
    sc = MFMA32(kf2, qf2, sc);
    sc = MFMA32(kf3, qf3, sc);

    // ---- causal mask (diagonal tile): kt = kv0 + (r&3) + 8*(r>>2) + 4*hi
    if (t == nT - 1) {
#pragma unroll
      for (int r = 0; r < 16; ++r) {
        int kt = kv0 + (r & 3) + 8 * (r >> 2) + 4 * hi;
        if (kt > q0 + ql) sc[r] = -INFINITY;
      }
    }

    // ---- online softmax: lane owns one q-row; cross-half via shfl_xor(32)
    float tm = fmaxf(fmaxf(fmaxf(sc[0], sc[1]), fmaxf(sc[2], sc[3])),
                     fmaxf(fmaxf(sc[4], sc[5]), fmaxf(sc[6], sc[7])));
    float tm2 = fmaxf(fmaxf(fmaxf(sc[8], sc[9]), fmaxf(sc[10], sc[11])),
                      fmaxf(fmaxf(sc[12], sc[13]), fmaxf(sc[14], sc[15])));
    tm = fmaxf(tm, tm2);
    tm = fmaxf(tm, __shfl_xor(tm, 32));      // full 32-row max, both halves
    if (__any(tm > m + 8.0f)) {              // defer-max (THR=8, exp2 domain)
      float mn = fmaxf(m, tm);
      float al = exp2f(m - mn);
      l *= al;
#pragma unroll
      for (int r = 0; r < 16; ++r) { accO0[r] *= al; accO1[r] *= al; }
      m = mn;
    }
    float p[16];
    float rs = 0.f;
#pragma unroll
    for (int r = 0; r < 16; ++r) {
      p[r] = exp2f(sc[r] - m);
      rs += p[r];
    }
    l += rs + __shfl_xor(rs, 32);

    // ---- P -> bf16 B-operand via cvt_pk + permlane32_swap (T12).
    unsigned a0 = packbf(p[0], p[1]),   b0 = packbf(p[4], p[5]);
    unsigned a1 = packbf(p[2], p[3]),   b1 = packbf(p[6], p[7]);
    unsigned a2 = packbf(p[8], p[9]),   b2 = packbf(p[12], p[13]);
    unsigned a3 = packbf(p[10], p[11]), b3 = packbf(p[14], p[15]);
    asm("v_permlane32_swap_b32 %0, %1" : "+v"(a0), "+v"(b0));
    asm("v_permlane32_swap_b32 %0, %1" : "+v"(a1), "+v"(b1));
    asm("v_permlane32_swap_b32 %0, %1" : "+v"(a2), "+v"(b2));
    asm("v_permlane32_swap_b32 %0, %1" : "+v"(a3), "+v"(b3));
    uint4v u0; u0[0] = a0; u0[1] = a1; u0[2] = b0; u0[3] = b1;
    uint4v u1; u1[0] = a2; u1[1] = a3; u1[2] = b2; u1[3] = b3;
    short8 pf0 = __builtin_bit_cast(short8, u0);   // kt chunk [kv0, kv0+16)
    short8 pf1 = __builtin_bit_cast(short8, u1);   // kt chunk [kv0+16, kv0+32)

    // ---- O^T += V^T P
    accO0 = MFMA32(vf00, pf0, accO0);
    accO0 = MFMA32(vf01, pf1, accO0);
    accO1 = MFMA32(vf10, pf0, accO1);
    accO1 = MFMA32(vf11, pf1, accO1);
  }

  // ---- 8-way merge: waves 1..7 dump (O^T, m, l); wave 0 combines + stores
  __syncthreads();
  if (w > 0) {
#pragma unroll
    for (int rq = 0; rq < 4; ++rq) {
      float4 t0, t1;
      t0.x = accO0[4 * rq]; t0.y = accO0[4 * rq + 1];
      t0.z = accO0[4 * rq + 2]; t0.w = accO0[4 * rq + 3];
      t1.x = accO1[4 * rq]; t1.y = accO1[4 * rq + 1];
      t1.z = accO1[4 * rq + 2]; t1.w = accO1[4 * rq + 3];
      lds_od[((w - 1) * 8 + rq) * 64 + lane] = t0;
      lds_od[((w - 1) * 8 + 4 + rq) * 64 + lane] = t1;
    }
    lds_ml[(w - 1) * 128 + lane] = m;
    lds_ml[(w - 1) * 128 + 64 + lane] = l;
  }
  __syncthreads();
  if (w == 0) {
    float mm[7], ll[7];
    float ms = m;
#pragma unroll
    for (int s = 0; s < 7; ++s) {
      mm[s] = lds_ml[s * 128 + lane];
      ll[s] = lds_ml[s * 128 + 64 + lane];
      ms = fmaxf(ms, mm[s]);
    }
    float c0 = exp2f(m - ms);
    float denom = c0 * l;
    float cs[7];
#pragma unroll
    for (int s = 0; s < 7; ++s) {
      cs[s] = exp2f(mm[s] - ms);
      denom += cs[s] * ll[s];
    }
    float inv = 1.0f / denom;
    float* orow = out + (size_t)(bb * TT + q0 + ql) * HH;
#pragma unroll
    for (int rq = 0; rq < 8; ++rq) {
      float o0, o1, o2, o3;
      if (rq < 4) {
        o0 = accO0[4 * (rq & 3)];     o1 = accO0[4 * (rq & 3) + 1];
        o2 = accO0[4 * (rq & 3) + 2]; o3 = accO0[4 * (rq & 3) + 3];
      } else {
        o0 = accO1[4 * (rq & 3)];     o1 = accO1[4 * (rq & 3) + 1];
        o2 = accO1[4 * (rq & 3) + 2]; o3 = accO1[4 * (rq & 3) + 3];
      }
      float4 res;
      res.x = c0 * o0; res.y = c0 * o1; res.z = c0 * o2; res.w = c0 * o3;
#pragma unroll
      for (int s = 0; s < 7; ++s) {
        float4 v = lds_od[(s * 8 + rq) * 64 + lane];
        res.x += cs[s] * v.x;
        res.y += cs[s] * v.y;
        res.z += cs[s] * v.z;
        res.w += cs[s] * v.w;
      }
      res.x *= inv; res.y *= inv; res.z *= inv; res.w *= inv;
      const int ht = rq >> 2, r2 = rq & 3;
      *(float4*)(orow + 32 * ht + 8 * r2 + 4 * hi) = res;
    }
  }
}

// ---------------------------------------------------------------------------
extern "C" void kernel_launch(void* const* d_in, const int* in_sizes, int n_in,
                              void* d_out, int out_size, void* d_ws, size_t ws_size,
                              hipStream_t stream) {
  const float* x  = (const float*)d_in[0];
  const float* Wq = (const float*)d_in[1];
  const float* bq = (const float*)d_in[2];
  const float* Wk = (const float*)d_in[3];
  const float* bk = (const float*)d_in[4];
  const float* Wv = (const float*)d_in[5];
  const float* bv = (const float*)d_in[6];
  float* out = (float*)d_out;

  char* ws = (char*)d_ws;
  short* Wt = (short*)ws;                           // 3*64*1024 bf16 = 384 KB
  short* qb = (short*)(ws + 393216);                // 16384*64 bf16 = 2 MB
  short* kb = qb + 16384 * 64;
  short* vT = kb + 16384 * 64;                      // total ~6.7 MB

  prep_wt<<<dim3(768), dim3(256), 0, stream>>>(Wq, Wk, Wv, Wt);
  qkv_gemm<<<dim3(256), dim3(512), 0, stream>>>(x, Wt, bq, bk, bv, qb, kb, vT);
  attn<<<dim3(512), dim3(512), 0, stream>>>(qb, kb, vT, out);
}